// Round 7
// baseline (610.212 us; speedup 1.0000x reference)
//
#include <hip/hip_runtime.h>

#define N_    64
#define CIN_  192
#define T_    256
#define V_    25
#define K_    3
#define COUT_ 64
#define OC_   192
#define SS_   5

#define OUT_OFF_A (N_*COUT_*T_*V_)          // 26214400
#define OUT_OFF_G (OUT_OFF_A + K_*V_*V_)    // 26216275

#define TCH   2              // t's per inner chunk
#define HCH   16             // chunks per block -> 32 t's per block
#define NCOLS 50             // TCH*V_
#define NCT   4              // 16-col tiles in GEMM1 (50 -> pad 64)
#define XB_STRIDE 200        // shorts per XB row (192 + 8 pad)
#define XB_ROWS 64           // NCT*16 (rows 50..63 stay zero from init)
#define XB_SH  (XB_ROWS*XB_STRIDE)            // 12800 shorts (single buffer)
#define YB_STRIDE 104        // shorts per YB row (75 -> pad 96 -> 104)
#define YB_ROWS 128          // TCH*64
#define YB_OFF  XB_SH
#define U_SHORTS (YB_OFF + YB_ROWS*YB_STRIDE) // 26112 shorts = 52224 B
#define NYV  4800            // OC_*V_ : per-n ybar size
#define CPN  (T_/(TCH*HCH))  // 8 chunk-blocks per n
#define NBLK (N_*CPN)        // 512 fused blocks = exactly 2/CU, one round
#define SUNITS (25*(CIN_/8)) // 600 staging units per chunk (col-pair x 8-ch group)
#define UPT 3                // ceil(SUNITS/256) units per thread
#define PTASKS 640           // partial-sum tasks: 64 cc x 10 kk-groups-of-8

// Barrier that does NOT drain vmcnt: each wave drains its own LDS ops
// (lgkmcnt(0)) so producer ds_writes are visible after s_barrier, but
// in-flight global loads/stores stay outstanding across the barrier.
// sched_barrier(0) on both sides pins memory ops (rule #18).
#define BAR_LDS() do {                                          \
    __builtin_amdgcn_sched_barrier(0);                          \
    asm volatile("s_waitcnt lgkmcnt(0)" ::: "memory");          \
    __builtin_amdgcn_s_barrier();                               \
    __builtin_amdgcn_sched_barrier(0);                          \
} while (0)

typedef __attribute__((ext_vector_type(8))) short short8;
typedef __attribute__((ext_vector_type(4))) float float4v;

__device__ inline unsigned bf16r(float f) {            // fp32 -> bf16 RNE
    unsigned u = __float_as_uint(f);
    return (u + 0x7fffu + ((u >> 16) & 1u)) >> 16;
}

// ---------- prep: WcB (bf16), A2T (Acat^T, bf16, zero-padded), A copy, ysum=0 --
__global__ __launch_bounds__(256) void prep(const float* __restrict__ Wc,
                                            const float* __restrict__ A,
                                            short* __restrict__ WcB,
                                            short* __restrict__ A2T,
                                            float* __restrict__ ysum,
                                            float* __restrict__ out) {
    int idx = blockIdx.x * 256 + threadIdx.x;
    if (idx < OC_ * CIN_) WcB[idx] = (short)bf16r(Wc[idx]);
    if (idx < 32 * YB_STRIDE) {           // A2T[w][kk], kk = k*25+v, zeros elsewhere
        int w = idx / YB_STRIDE, kk = idx - w * YB_STRIDE;
        short val = 0;
        if (w < V_ && kk < K_ * V_) {
            int k = kk / V_, v = kk - k * V_;
            val = (short)bf16r(A[k * V_ * V_ + v * V_ + w]);
        }
        A2T[idx] = val;
    }
    if (idx < K_ * V_ * V_) out[OUT_OFF_A + idx] = A[idx];
    if (idx < N_ * NYV) ysum[idx] = 0.f;  // atomic accumulation target for fused
}

// ---------- fused MFMA: y = Wc@x+bc, out = Ycat@Acat, ybar sums via atomics ----
// Pipelined staging (R6): chunk h+1's 24 global loads issue right after B0(h),
// pinned by sched_barrier(0). b2 reloaded per chunk (L2-hot) to pay the tmp
// bill. lgkmcnt-only barriers keep vmem in flight across B0/B1.
// R7: partials vectorized — task (cc, kk-group-of-8), 2x ds_read_b128 per task
// instead of 38 scalar ds_read_u16 per thread; s_setprio(1) around MFMA
// clusters (2 independent blocks/CU -> scheduler has roles to arbitrate).
// Pad-correctness: A2T cols [75,96) are exact zeros; XB rows 50..63 / YB pad
// cols keep the one-time zero init or finite bf16; pad kk's accumulate zeros
// into racc and are skipped at flush.
__global__ __launch_bounds__(256, 2) void fused_mfma(const float* __restrict__ x,
                                                     const short* __restrict__ WcB,
                                                     const float* __restrict__ bc,
                                                     const short* __restrict__ A2T,
                                                     float* __restrict__ out,
                                                     float* __restrict__ ysum) {
    __shared__ __align__(16) short U[U_SHORTS];

    const int tid  = threadIdx.x;
    const int lane = tid & 63;
    const int wv   = tid >> 6;
    const int l15  = lane & 15;
    const int q    = lane >> 4;
    const int n    = blockIdx.x >> 3;
    const int tc   = blockIdx.x & 7;
    const int rt0  = wv * 3;

    // one-time zero: every byte of U is finite forever after
    {
        int4 z = make_int4(0, 0, 0, 0);
        for (int i = tid; i < U_SHORTS / 8; i += 256) ((int4*)U)[i] = z;
    }
    __syncthreads();

    // Wc A-fragments resident in registers (72 VGPR): wave wv owns rows [wv*48,+48)
    short8 wfrag[3][6];
    {
        const short* wb = WcB + (rt0 * 16 + l15) * CIN_ + q * 8;
#pragma unroll
        for (int j = 0; j < 3; ++j)
#pragma unroll
            for (int ks = 0; ks < 6; ++ks)
                wfrag[j][ks] = *(const short8*)(wb + j * 16 * CIN_ + ks * 32);
    }
    float4v bvec[3];
#pragma unroll
    for (int j = 0; j < 3; ++j)
        bvec[j] = *(const float4v*)(bc + (rt0 + j) * 16 + q * 4);

    // partial-sum accumulators: task s -> (cc, kk-group), 8 f32 each
    float racc[UPT][8];
#pragma unroll
    for (int s = 0; s < UPT; ++s)
#pragma unroll
        for (int e = 0; e < 8; ++e) racc[s][e] = 0.f;

    const float* xn = x + (size_t)n * (CIN_ * T_ * V_);
    const int tbase = tc * (TCH * HCH);

    // prologue: stage chunk 0 (synchronous, once per block)
    for (int u = tid; u < SUNITS; u += 256) {
        int col2 = u % 25, cg = u / 25;
        const float* xp = xn + (size_t)(cg * 8) * (T_ * V_) + tbase * V_ + col2 * 2;
        short8 a, b;
#pragma unroll
        for (int j = 0; j < 8; ++j) {
            float2 f = *(const float2*)(xp + (size_t)j * (T_ * V_));
            a[j] = (short)bf16r(f.x);
            b[j] = (short)bf16r(f.y);
        }
        *(short8*)&U[(col2 * 2 + 0) * XB_STRIDE + cg * 8] = a;
        *(short8*)&U[(col2 * 2 + 1) * XB_STRIDE + cg * 8] = b;
    }

    for (int h = 0; h < HCH; ++h) {
        const int t0 = tbase + h * TCH;
        const bool stage_ok = (h < HCH - 1);

        BAR_LDS();         // B0: XB(h) ready; YB(h-1) readers done

        // ---- prefetch: issue chunk h+1's 24 global loads NOW, pinned ----
        float2 tmp[UPT][8];
        if (stage_ok) {
#pragma unroll
            for (int s = 0; s < UPT; ++s) {
                int u = tid + s * 256;
                if (u < SUNITS) {
                    int col2 = u % 25, cg = u / 25;
                    const float* xp = xn + (size_t)(cg * 8) * (T_ * V_) + (t0 + TCH) * V_ + col2 * 2;
#pragma unroll
                    for (int j = 0; j < 8; ++j)
                        tmp[s][j] = *(const float2*)(xp + (size_t)j * (T_ * V_));
                }
            }
            __builtin_amdgcn_sched_barrier(0);   // loads may not sink past here
        }

        // ---- GEMM1: acc[j][ct], K=192=6*32, wfrag resident ----
        float4v acc[3][NCT];
#pragma unroll
        for (int j = 0; j < 3; ++j)
#pragma unroll
            for (int ct = 0; ct < NCT; ++ct) acc[j][ct] = bvec[j];

        __builtin_amdgcn_s_setprio(1);
#pragma unroll
        for (int ct = 0; ct < NCT; ++ct) {
            const short* xb = &U[(ct * 16 + l15) * XB_STRIDE + q * 8];
#pragma unroll
            for (int ks = 0; ks < 6; ++ks) {
                short8 bfrag = *(const short8*)(xb + ks * 32);
#pragma unroll
                for (int j = 0; j < 3; ++j)
                    acc[j][ct] = __builtin_amdgcn_mfma_f32_16x16x32_bf16(
                        wfrag[j][ks], bfrag, acc[j][ct], 0, 0, 0);
            }
        }
        __builtin_amdgcn_s_setprio(0);

        // ---- Ywrite: acc -> YB[(tl*64+cc)][k*25+v] (pad cols stay zero) ----
#pragma unroll
        for (int ct = 0; ct < NCT; ++ct) {
            int col = ct * 16 + l15;
            if (col < NCOLS) {
                int tl = col / V_;
                int v  = col - tl * V_;
#pragma unroll
                for (int j = 0; j < 3; ++j) {
                    int obase = (rt0 + j) * 16 + q * 4;
#pragma unroll
                    for (int i = 0; i < 4; ++i) {
                        int o   = obase + i;
                        int row = tl * 64 + (o & 63);
                        int cY  = (o >> 6) * V_ + v;
                        U[YB_OFF + row * YB_STRIDE + cY] = (short)bf16r(acc[j][ct][i]);
                    }
                }
            }
        }

        BAR_LDS();         // B1: YB(h) published; XB(h) readers done; vmem flies on

        // ---- GEMM2: Out[(t,cc)=128][w pad 32] = Ycat[128][pad96] @ Acat ----
        // b2 reloaded per chunk (L2-hot; frees 24 regs for the prefetch tmp)
        short8 b2[2][3];
#pragma unroll
        for (int nt = 0; nt < 2; ++nt)
#pragma unroll
            for (int ks = 0; ks < 3; ++ks)
                b2[nt][ks] = *(const short8*)&A2T[(nt * 16 + l15) * YB_STRIDE + ks * 32 + q * 8];

        float4v o2[2][2];
#pragma unroll
        for (int mt = 0; mt < 2; ++mt)
#pragma unroll
            for (int nt = 0; nt < 2; ++nt) o2[mt][nt] = (float4v){0.f, 0.f, 0.f, 0.f};

        __builtin_amdgcn_s_setprio(1);
#pragma unroll
        for (int mt = 0; mt < 2; ++mt) {
            int m = (wv * 2 + mt) * 16 + l15;
            const short* yb = &U[YB_OFF + m * YB_STRIDE + q * 8];
#pragma unroll
            for (int ks = 0; ks < 3; ++ks) {
                short8 af = *(const short8*)(yb + ks * 32);
#pragma unroll
                for (int nt = 0; nt < 2; ++nt)
                    o2[mt][nt] = __builtin_amdgcn_mfma_f32_16x16x32_bf16(
                        af, b2[nt][ks], o2[mt][nt], 0, 0, 0);
            }
        }
        __builtin_amdgcn_s_setprio(0);

        // store out[n, cc, t0+tl, w]
#pragma unroll
        for (int mt = 0; mt < 2; ++mt) {
#pragma unroll
            for (int nt = 0; nt < 2; ++nt) {
                int w = nt * 16 + l15;
                if (w < V_) {
#pragma unroll
                    for (int i = 0; i < 4; ++i) {
                        int m  = (wv * 2 + mt) * 16 + q * 4 + i;
                        int cc = m & 63, tl = m >> 6;
                        out[((size_t)(n * COUT_ + cc) * T_ + (t0 + tl)) * V_ + w] = o2[mt][nt][i];
                    }
                }
            }
        }

        // ---- y t-partials, vectorized: task (cc, kk-group), 2x ds_read_b128 ----
#pragma unroll
        for (int s = 0; s < UPT; ++s) {
            int tau = s * 256 + tid;
            if (tau < PTASKS) {
                int cc = tau / 10, g = tau - (tau / 10) * 10;
                const short* yp = &U[YB_OFF + cc * YB_STRIDE + g * 8];
#pragma unroll
                for (int tl = 0; tl < TCH; ++tl) {
                    short8 y8 = *(const short8*)(yp + tl * 64 * YB_STRIDE);
#pragma unroll
                    for (int e = 0; e < 8; ++e) {
                        unsigned b = (unsigned short)y8[e];
                        racc[s][e] += __uint_as_float(b << 16);
                    }
                }
            }
        }

        // ---- chunk tail: convert tmp + publish XB(h+1) (safe after B1) ----
        if (stage_ok) {
#pragma unroll
            for (int s = 0; s < UPT; ++s) {
                int u = tid + s * 256;
                if (u < SUNITS) {
                    int col2 = u % 25, cg = u / 25;
                    short8 a, b;
#pragma unroll
                    for (int j = 0; j < 8; ++j) {
                        a[j] = (short)bf16r(tmp[s][j].x);
                        b[j] = (short)bf16r(tmp[s][j].y);
                    }
                    *(short8*)&U[(col2 * 2 + 0) * XB_STRIDE + cg * 8] = a;
                    *(short8*)&U[(col2 * 2 + 1) * XB_STRIDE + cg * 8] = b;
                }
            }
        }
    }

    // flush partials: atomic accumulate into ysum[n]; skip pad kk >= 75
    float* yb = ysum + (size_t)n * NYV;
#pragma unroll
    for (int s = 0; s < UPT; ++s) {
        int tau = s * 256 + tid;
        if (tau < PTASKS) {
            int cc = tau / 10, g = tau - (tau / 10) * 10;
#pragma unroll
            for (int e = 0; e < 8; ++e) {
                int kk = g * 8 + e;
                if (kk < K_ * V_) {
                    int k = kk / V_, v = kk - k * V_;
                    atomicAdd(&yb[(k * COUT_ + cc) * V_ + v], racc[s][e]);
                }
            }
        }
    }
}

// ---------- e2: x1m/x2m -> sem -> graphs; block = (n, 10 j's x 25 v) ------------
// ysum holds raw sum over t; the 1/T mean-scale is folded in at the end.
__global__ __launch_bounds__(256) void e2_graphs(const float* __restrict__ ysum,
                                                 const float* __restrict__ W1,
                                                 const float* __restrict__ b1,
                                                 const float* __restrict__ W2,
                                                 const float* __restrict__ b2,
                                                 const int* __restrict__ node_type,
                                                 float* __restrict__ out) {
    __shared__ float s1[10][V_];
    __shared__ float sem[10];
    const int tid = threadIdx.x;
    const int n  = blockIdx.x >> 5;
    const int jc = blockIdx.x & 31;
    const int jl = tid / V_;
    const int v  = tid - jl * V_;
    const int j  = jc * 10 + jl;
    float x2 = 0.f;
    if (jl < 10) {
        const float* yb = ysum + (size_t)n * NYV + v;
        const float* w1 = W1 + j * OC_;
        const float* w2 = W2 + j * OC_;
        float a1 = 0.f, a2 = 0.f;
        for (int o = 0; o < OC_; ++o) {
            float yv = yb[o * V_];
            a1 += w1[o] * yv;
            a2 += w2[o] * yv;
        }
        s1[jl][v] = b1[j] + a1 * (1.0f / T_);
        x2 = b2[j] + a2 * (1.0f / T_);
    }
    __syncthreads();
    if (tid < 10) {
        int s = (jc * 10 + tid) >> 6;   // semantic index = j / 64
        float sum = 0.f, cnt = 0.f;
        for (int vv = 0; vv < V_; ++vv)
            if (node_type[vv] == s) { sum += s1[tid][vv]; cnt += 1.f; }
        sem[tid] = sum / cnt;
    }
    __syncthreads();
    if (jl < 10)
        out[OUT_OFF_G + (size_t)n * (SS_ * COUT_ * V_) + j * V_ + v] = sem[jl] - x2;
}

extern "C" void kernel_launch(void* const* d_in, const int* in_sizes, int n_in,
                              void* d_out, int out_size, void* d_ws, size_t ws_size,
                              hipStream_t stream) {
    const float* x         = (const float*)d_in[0];
    const float* A         = (const float*)d_in[1];
    const int*   node_type = (const int*)d_in[2];
    const float* Wc        = (const float*)d_in[3];
    const float* bc        = (const float*)d_in[4];
    const float* W1        = (const float*)d_in[5];
    const float* b1        = (const float*)d_in[6];
    const float* W2        = (const float*)d_in[7];
    const float* b2        = (const float*)d_in[8];
    float* out = (float*)d_out;

    float* ysum = (float*)d_ws;                    // 307200 floats (atomic target)
    short* WcB  = (short*)(ysum + N_ * NYV);       // 36864 shorts
    short* A2T  = WcB + OC_ * CIN_;                // 3328 shorts

    // prep grid must cover ysum zeroing: N_*NYV = 307200 -> 1200 blocks
    hipLaunchKernelGGL(prep, dim3((N_ * NYV + 255) / 256), dim3(256), 0, stream,
                       Wc, A, WcB, A2T, ysum, out);
    hipLaunchKernelGGL(fused_mfma, dim3(NBLK), dim3(256), 0, stream,
                       x, WcB, bc, A2T, out, ysum);
    hipLaunchKernelGGL(e2_graphs, dim3(N_ * 32), dim3(256), 0, stream,
                       ysum, W1, b1, W2, b2, node_type, out);
}